// Round 9
// baseline (30.765 us; speedup 1.0000x reference)
//
#include <hip/hip_runtime.h>

// PhysConstrainedLES: fused divergence + pressure-Poisson RHS stencils.
// uPred: [B,2,H,W] f32, pPred: [B,1,H,W] f32
// out:  div [B,510,512] then pstar [B,510,510], concatenated flat, f32.
//
// R9: 4 cols x 4 output rows per thread (6 input rows, 18 float4 loads all
// issued up front -> 18-deep MLP, 1.5x L2-side row amplification vs 2x in
// R8 / 3x in R3). All load/store instructions lane-contiguous (wc = tid*4;
// R5/R6 lesson: never gap lanes within one instruction).
// Per batch: 127 quad blocks (rows 4*rp..4*rp+3) + 1 tail pair block
// (rows 508-509); branch is block-uniform. NBLK = 4096 (divisible by 8).
// div stores non-temporal (full-line coverage verified in R7).

#define BN 32
#define HH 512
#define WW 512
#define OH 510
#define OW2 510
#define BPB 128            // per batch: 127 quads + 1 tail pair
#define NBLK (BPB * BN)    // 4096

typedef float f32x4 __attribute__((ext_vector_type(4)));

__device__ __forceinline__ float clip1(float x) {
    return fminf(fmaxf(x, -1.0f), 1.0f);
}

__global__ __launch_bounds__(128) void pcles_kernel(
    const float* __restrict__ u_,   // [B,2,H,W]
    const float* __restrict__ p_,   // [B,1,H,W]
    float* __restrict__ div_out,    // [B,510,512]
    float* __restrict__ ps_out)     // [B,510,510]
{
    // bijective XCD swizzle: consecutive nb (adjacent quads, shared halo
    // rows) land on the same XCD L2.
    const int bid = blockIdx.x;
    const int nb  = (bid & 7) * (NBLK / 8) + (bid >> 3);
    const int b   = nb / BPB;
    const int rp  = nb % BPB;
    const int hA  = rp * 4;                        // tail: rp=127 -> hA=508
    const int nrows = (rp < BPB - 1) ? 4 : 2;      // output rows this block

    const int tid  = (int)threadIdx.x;
    const int wc   = tid * 4;        // 0..508, lane-contiguous
    const int lane = tid & 63;

    const float* ub = u_ + (size_t)b * 2 * HH * WW;
    const float* vb = ub + HH * WW;
    const float* pb = p_ + (size_t)b * HH * WW;

    // input rows hA..hA+5 (tail clamps 512,513 -> 511; results unstored)
    int ri[6];
    #pragma unroll
    for (int i = 0; i < 6; ++i) ri[i] = (hA + i < HH) ? hA + i : HH - 1;

    // 18 independent, perfectly coalesced float4 loads, all issued up front
    float4 tu[6], tv[6], tp[6];
    #pragma unroll
    for (int i = 0; i < 6; ++i) {
        tu[i] = *(const float4*)(ub + ri[i] * WW + wc);
        tv[i] = *(const float4*)(vb + ri[i] * WW + wc);
        tp[i] = *(const float4*)(pb + ri[i] * WW + wc);
    }

    // halo columns via intra-wave shuffles (34 total)
    float uL[6], uR[6], uS[6], vR[6], vS[6], pR[6], pS[6];
    #pragma unroll
    for (int i = 0; i < 6; ++i) {
        uR[i] = __shfl_down(tu[i].x, 1);   // col wc+4
        vR[i] = __shfl_down(tv[i].x, 1);
        pR[i] = __shfl_down(tp[i].x, 1);
    }
    #pragma unroll
    for (int i = 1; i < 5; ++i) {          // mid rows only
        uL[i] = __shfl_up(tu[i].w, 1);     // col wc-1
        uS[i] = __shfl_down(tu[i].y, 1);   // col wc+5
        vS[i] = __shfl_down(tv[i].y, 1);
        pS[i] = __shfl_down(tp[i].y, 1);
    }
    uL[0] = uL[5] = uS[0] = uS[5] = 0.0f;  // never read
    vS[0] = vS[5] = pS[0] = pS[5] = 0.0f;

    // wave-edge fixups (clamped cols give replicate-pad at true edges)
    const int cL = (wc > 0) ? wc - 1 : 0;
    const int c4 = (wc + 4 < WW) ? wc + 4 : WW - 1;
    const int c5 = (wc + 5 < WW) ? wc + 5 : WW - 1;
    if (lane == 0) {
        #pragma unroll
        for (int i = 1; i < 5; ++i) uL[i] = ub[ri[i] * WW + cL];
    }
    if (lane == 63) {
        #pragma unroll
        for (int i = 0; i < 6; ++i) {
            uR[i] = ub[ri[i] * WW + c4];
            vR[i] = vb[ri[i] * WW + c4];
            pR[i] = pb[ri[i] * WW + c4];
        }
        #pragma unroll
        for (int i = 1; i < 5; ++i) {
            uS[i] = ub[ri[i] * WW + c5];
            vS[i] = vb[ri[i] * WW + c5];
            pS[i] = pb[ri[i] * WW + c5];
        }
    }

    // windows: uw[i] cols wc-1..wc+5 ; vw/pw[i] cols wc..wc+5
    float uw[6][7], vw[6][6], pw[6][6];
    #pragma unroll
    for (int i = 0; i < 6; ++i) {
        uw[i][0] = uL[i]; uw[i][1] = tu[i].x; uw[i][2] = tu[i].y;
        uw[i][3] = tu[i].z; uw[i][4] = tu[i].w; uw[i][5] = uR[i]; uw[i][6] = uS[i];
        vw[i][0] = tv[i].x; vw[i][1] = tv[i].y; vw[i][2] = tv[i].z;
        vw[i][3] = tv[i].w; vw[i][4] = vR[i]; vw[i][5] = vS[i];
        pw[i][0] = tp[i].x; pw[i][1] = tp[i].y; pw[i][2] = tp[i].z;
        pw[i][3] = tp[i].w; pw[i][4] = pR[i]; pw[i][5] = pS[i];
    }

    float dv[4][4], ps[4][4];
    #pragma unroll
    for (int k = 0; k < 4; ++k) {          // output row hA+k; rows k,k+1,k+2
        #pragma unroll
        for (int j = 0; j < 4; ++j) {
            const float dudx = (uw[k + 1][j + 2] - uw[k + 1][j]) * 50.0f;
            const float dvdy = (vw[k + 2][j] - vw[k][j]) * 50.0f;
            dv[k][j] = clip1(0.01f * (dvdy + dudx));

            const float pc  = pw[k + 1][j + 1];
            const float ddp = (pw[k + 1][j] - 2.0f * pc + pw[k + 1][j + 2]) * 1.0e4f
                            + (pw[k][j + 1] - 2.0f * pc + pw[k + 2][j + 1]) * 1.0e4f;
            const float ux = (uw[k + 1][j + 3] - uw[k + 1][j + 1]) * 50.0f;
            const float uy = (uw[k + 2][j + 2] - uw[k][j + 2]) * 50.0f;
            const float vx = (vw[k + 1][j + 2] - vw[k + 1][j]) * 50.0f;
            const float vy = (vw[k + 2][j + 1] - vw[k][j + 1]) * 50.0f;
            const float rhs = ux * ux + 2.0f * uy * vx + vy * vy;
            ps[k][j] = clip1(1.0e-4f * (ddp + rhs));
        }
    }

    // div: non-temporal full-line stores; pstar: plain float2 stores
    float* dr0 = div_out + ((size_t)b * OH + hA) * WW + wc;
    float* pw0 = ps_out + ((size_t)b * OH + hA) * OW2 + wc;
    #pragma unroll
    for (int k = 0; k < 4; ++k) {
        if (k < nrows) {
            f32x4 t = {dv[k][0], dv[k][1], dv[k][2], dv[k][3]};
            __builtin_nontemporal_store(t, (f32x4*)(dr0 + (size_t)k * WW));
            float* pk = pw0 + (size_t)k * OW2;
            *(float2*)pk = make_float2(ps[k][0], ps[k][1]);
            if (wc + 2 < OW2) *(float2*)(pk + 2) = make_float2(ps[k][2], ps[k][3]);
        }
    }
}

extern "C" void kernel_launch(void* const* d_in, const int* in_sizes, int n_in,
                              void* d_out, int out_size, void* d_ws, size_t ws_size,
                              hipStream_t stream) {
    const float* uPred = (const float*)d_in[0];
    const float* pPred = (const float*)d_in[1];
    float* div_out = (float*)d_out;
    float* ps_out  = div_out + (size_t)BN * OH * WW;

    pcles_kernel<<<dim3(NBLK), dim3(128), 0, stream>>>(uPred, pPred, div_out, ps_out);
}

// Round 10
// 29.350 us; speedup vs baseline: 1.0482x; 1.0482x over previous
//
#include <hip/hip_runtime.h>

// PhysConstrainedLES: fused divergence + pressure-Poisson RHS stencils.
// uPred: [B,2,H,W] f32, pPred: [B,1,H,W] f32
// out:  div [B,510,512] then pstar [B,510,510], concatenated flat, f32.
//
// FINAL (R7 structure, best measured: 29.48us timed). One output row per
// block, 128 thr x 4 cols, 32640 waves. Halos via intra-wave shuffles +
// lane-edge scalar loads (clamped cols realize replicate-pad). div stores
// non-temporal (full-line coverage -> no write inflation, verified R7).
// Session conclusions: memory-side roofline at ~162 MB/replay -> 5.5 TB/s
// effective (87% of 6.29 TB/s copy ceiling). Wider per-thread tiles (R8/R9)
// and wave-per-row (R6) all converge at or above this time; NT pstar stores
// (R5) inflate writes 1.6x due to sub-line coverage.

#define BN 32
#define HH 512
#define WW 512
#define OH 510
#define OW2 510
#define NBLK (OH * BN)   // 16320, divisible by 8

typedef float f32x4 __attribute__((ext_vector_type(4)));

__device__ __forceinline__ float clip1(float x) {
    return fminf(fmaxf(x, -1.0f), 1.0f);
}

__global__ __launch_bounds__(128) void pcles_kernel(
    const float* __restrict__ u_,   // [B,2,H,W]
    const float* __restrict__ p_,   // [B,1,H,W]
    float* __restrict__ div_out,    // [B,510,512]
    float* __restrict__ ps_out)     // [B,510,510]
{
    // bijective XCD swizzle: XCD k gets nb in [k*2040, (k+1)*2040) ->
    // consecutive h within a batch on one XCD -> vertical reuse in its L2.
    const int bid = blockIdx.x;
    const int nb  = (bid & 7) * (NBLK / 8) + (bid >> 3);
    const int b   = nb / OH;
    const int h   = nb % OH;

    const int tid  = (int)threadIdx.x;
    const int wc   = tid * 4;        // 0..508
    const int lane = tid & 63;

    const float* ub = u_ + (size_t)b * 2 * HH * WW;
    const float* vb = ub + HH * WW;
    const float* pb = p_ + (size_t)b * HH * WW;

    const float* ur0 = ub + h * WW;          // rows h, h+1, h+2
    const float* vr0 = vb + h * WW;
    const float* pr0 = pb + h * WW;

    // 9 independent vector loads (MLP)
    const float4 tu0 = *(const float4*)(ur0 + wc);
    const float4 tu1 = *(const float4*)(ur0 + WW + wc);
    const float4 tu2 = *(const float4*)(ur0 + 2 * WW + wc);
    const float4 tv0 = *(const float4*)(vr0 + wc);
    const float4 tv1 = *(const float4*)(vr0 + WW + wc);
    const float4 tv2 = *(const float4*)(vr0 + 2 * WW + wc);
    const float4 tp0 = *(const float4*)(pr0 + wc);
    const float4 tp1 = *(const float4*)(pr0 + WW + wc);
    const float4 tp2 = *(const float4*)(pr0 + 2 * WW + wc);

    // halo columns via shuffles (wave-internal); fix wave-edge lanes below
    float uL1   = __shfl_up(tu1.w, 1);     // col wc-1, row h+1
    float uR1_0 = __shfl_down(tu0.x, 1);   // col wc+4, row h
    float uR1_1 = __shfl_down(tu1.x, 1);   // col wc+4, row h+1
    float uR1_2 = __shfl_down(tu2.x, 1);   // col wc+4, row h+2
    float uR2_1 = __shfl_down(tu1.y, 1);   // col wc+5, row h+1
    float vR1_0 = __shfl_down(tv0.x, 1);
    float vR1_1 = __shfl_down(tv1.x, 1);
    float vR1_2 = __shfl_down(tv2.x, 1);
    float vR2_1 = __shfl_down(tv1.y, 1);
    float pR1_0 = __shfl_down(tp0.x, 1);
    float pR1_1 = __shfl_down(tp1.x, 1);
    float pR1_2 = __shfl_down(tp2.x, 1);
    float pR2_1 = __shfl_down(tp1.y, 1);

    const int cL = (wc > 0) ? wc - 1 : 0;              // replicate-pad clamp
    const int c4 = (wc + 4 < WW) ? wc + 4 : WW - 1;
    const int c5 = (wc + 5 < WW) ? wc + 5 : WW - 1;
    if (lane == 0)  uL1 = ur0[WW + cL];
    if (lane == 63) {
        uR1_0 = ur0[c4];          uR1_1 = ur0[WW + c4];  uR1_2 = ur0[2 * WW + c4];
        uR2_1 = ur0[WW + c5];
        vR1_0 = vr0[c4];          vR1_1 = vr0[WW + c4];  vR1_2 = vr0[2 * WW + c4];
        vR2_1 = vr0[WW + c5];
        pR1_0 = pr0[c4];          pR1_1 = pr0[WW + c4];  pR1_2 = pr0[2 * WW + c4];
        pR2_1 = pr0[WW + c5];
    }

    // register windows (constant-indexed -> stay in VGPRs)
    const float u0[5] = {tu0.x, tu0.y, tu0.z, tu0.w, uR1_0};             // cols wc..wc+4
    const float u1[7] = {uL1, tu1.x, tu1.y, tu1.z, tu1.w, uR1_1, uR2_1}; // cols wc-1..wc+5
    const float u2[5] = {tu2.x, tu2.y, tu2.z, tu2.w, uR1_2};
    const float v0[5] = {tv0.x, tv0.y, tv0.z, tv0.w, vR1_0};
    const float v1[6] = {tv1.x, tv1.y, tv1.z, tv1.w, vR1_1, vR2_1};     // cols wc..wc+5
    const float v2[5] = {tv2.x, tv2.y, tv2.z, tv2.w, vR1_2};
    const float p0[5] = {tp0.x, tp0.y, tp0.z, tp0.w, pR1_0};
    const float p1[6] = {tp1.x, tp1.y, tp1.z, tp1.w, pR1_1, pR2_1};
    const float p2[5] = {tp2.x, tp2.y, tp2.z, tp2.w, pR1_2};

    float dv[4], ps[4];
    #pragma unroll
    for (int j = 0; j < 4; ++j) {
        const float dudx = (u1[j + 2] - u1[j]) * 50.0f;
        const float dvdy = (v2[j] - v0[j]) * 50.0f;
        dv[j] = clip1(0.01f * (dvdy + dudx));

        const float pc  = p1[j + 1];
        const float ddp = (p1[j] - 2.0f * pc + p1[j + 2]) * 1.0e4f
                        + (p0[j + 1] - 2.0f * pc + p2[j + 1]) * 1.0e4f;
        const float ux = (u1[j + 3] - u1[j + 1]) * 50.0f;
        const float uy = (u2[j + 1] - u0[j + 1]) * 50.0f;
        const float vx = (v1[j + 2] - v1[j]) * 50.0f;
        const float vy = (v2[j + 1] - v0[j + 1]) * 50.0f;
        const float rhs = ux * ux + 2.0f * uy * vx + vy * vy;
        ps[j] = clip1(1.0e-4f * (ddp + rhs));
    }

    // div: non-temporal full-line store (lane-contiguous 1KB per wave instr)
    float* dr = div_out + ((size_t)b * OH + h) * WW + wc;
    f32x4 dvv = {dv[0], dv[1], dv[2], dv[3]};
    __builtin_nontemporal_store(dvv, (f32x4*)dr);

    // pstar: plain stores (rows 8B-aligned; let L2 write-combine)
    float* pr = ps_out + ((size_t)b * OH + h) * OW2 + wc;
    *(float2*)pr = make_float2(ps[0], ps[1]);
    if (wc + 2 < OW2) *(float2*)(pr + 2) = make_float2(ps[2], ps[3]);
}

extern "C" void kernel_launch(void* const* d_in, const int* in_sizes, int n_in,
                              void* d_out, int out_size, void* d_ws, size_t ws_size,
                              hipStream_t stream) {
    const float* uPred = (const float*)d_in[0];
    const float* pPred = (const float*)d_in[1];
    float* div_out = (float*)d_out;
    float* ps_out  = div_out + (size_t)BN * OH * WW;

    pcles_kernel<<<dim3(NBLK), dim3(128), 0, stream>>>(uPred, pPred, div_out, ps_out);
}